// Round 6
// baseline (810.146 us; speedup 1.0000x reference)
//
#include <hip/hip_runtime.h>

#define N_NODES 50000
#define N_EDGES 800000
#define HEADS 4
#define NUM_GRAPHS 8

// ============ CSR build ============
__global__ __launch_bounds__(256) void hist_kernel(const int* __restrict__ dst,
                                                   int* __restrict__ deg) {
  int e = blockIdx.x * blockDim.x + threadIdx.x;
  if (e < N_EDGES) atomicAdd(&deg[dst[e]], 1);
}

// Wave-aggregated bump allocation: rowstart[i] = arbitrary contiguous segment
// of length deg[i]. Cross-node order is irrelevant for correctness.
__global__ __launch_bounds__(256) void alloc_kernel(const int* __restrict__ deg,
                                                    int* __restrict__ gctr,
                                                    int* __restrict__ rowstart,
                                                    int* __restrict__ cursor) {
  int i = blockIdx.x * blockDim.x + threadIdx.x;
  int lane = threadIdx.x & 63;
  int d = (i < N_NODES) ? deg[i] : 0;
  int pre = d;
#pragma unroll
  for (int off = 1; off < 64; off <<= 1) {
    int v = __shfl_up(pre, off, 64);
    if (lane >= off) pre += v;
  }
  int total = __shfl(pre, 63, 64);
  int base = 0;
  if (lane == 63) base = atomicAdd(gctr, total);
  base = __shfl(base, 63, 64);
  if (i < N_NODES) {
    int start = base + pre - d;
    rowstart[i] = start;
    cursor[i] = start;
  }
}

// src_perm[slot] = src[e]  (the one unavoidable random scatter)
__global__ __launch_bounds__(256) void scatter_kernel(const int* __restrict__ src,
                                                      const int* __restrict__ dst,
                                                      int* __restrict__ cursor,
                                                      int* __restrict__ src_perm) {
  int e = blockIdx.x * blockDim.x + threadIdx.x;
  if (e >= N_EDGES) return;
  int p = atomicAdd(&cursor[dst[e]], 1);
  src_perm[p] = src[e];
}

// ============ fc0: h0 = relu(x@W0+b0) [N,16] ============
__global__ __launch_bounds__(256) void fc0_kernel(
    const float* __restrict__ x,
    const float* __restrict__ fc0_w, const float* __restrict__ fc0_b,
    float* __restrict__ h0) {
  __shared__ float sW0[3 * 16];
  __shared__ float sB0[16];
  for (int i = threadIdx.x; i < 48; i += blockDim.x) sW0[i] = fc0_w[i];
  for (int i = threadIdx.x; i < 16; i += blockDim.x) sB0[i] = fc0_b[i];
  __syncthreads();
  int n = blockIdx.x * blockDim.x + threadIdx.x;
  if (n >= N_NODES) return;
  float x0 = x[n * 3 + 0], x1 = x[n * 3 + 1], x2 = x[n * 3 + 2];
#pragma unroll
  for (int j = 0; j < 16; j++) {
    float v = x0 * sW0[0 * 16 + j] + x1 * sW0[1 * 16 + j] + x2 * sW0[2 * 16 + j] + sB0[j];
    h0[(size_t)n * 16 + j] = fmaxf(v, 0.f);
  }
}

// ============ Fused q+agg, layer 1 (CIN=16) ============
// One wave per node: lane = hh*16 + j. Per edge: gather h0[src] row across
// j-lanes, compute head logits via xor-shuffle dots, softmax across the 4
// 16-lane head groups, accumulate q*f. No atomics, no LDS, no q buffer.
__global__ __launch_bounds__(256) void agg1_fused(
    const int* __restrict__ rowstart, const int* __restrict__ deg,
    const int* __restrict__ src_perm,
    const float* __restrict__ h0,
    const float* __restrict__ u1, const float* __restrict__ c1,
    float* __restrict__ A) {
  int wave = threadIdx.x >> 6;
  int lane = threadIdx.x & 63;
  int hh = lane >> 4, j = lane & 15;
  int node = blockIdx.x * 4 + wave;
  if (node >= N_NODES) return;
  float uw = u1[j * 4 + hh];
  float cbv = c1[hh];
  float hd = h0[(size_t)node * 16 + j];
  int e0 = rowstart[node];
  int e1 = e0 + deg[node];
  float acc = 0.f;
  for (int p = e0; p < e1; p++) {
    int s = src_perm[p];
    float f = h0[(size_t)s * 16 + j];
    float v = (f - hd) * uw;
    v += __shfl_xor(v, 1, 64);
    v += __shfl_xor(v, 2, 64);
    v += __shfl_xor(v, 4, 64);
    v += __shfl_xor(v, 8, 64);
    float logit = v + cbv;
    float m = logit;
    m = fmaxf(m, __shfl_xor(m, 16, 64));
    m = fmaxf(m, __shfl_xor(m, 32, 64));
    float ex = __expf(logit - m);
    float es = ex;
    es += __shfl_xor(es, 16, 64);
    es += __shfl_xor(es, 32, 64);
    acc += (ex / es) * f;
  }
  A[(size_t)node * 64 + lane] = acc;  // A[node][hh*16+j]
}

// ============ Fused q+agg, layer 2 (CIN=32) ============
// One wave per node: lane = hp*32 + j, each lane covers heads {hp, hp+2}.
__global__ __launch_bounds__(256) void agg2_fused(
    const int* __restrict__ rowstart, const int* __restrict__ deg,
    const int* __restrict__ src_perm,
    const float* __restrict__ h1,
    const float* __restrict__ u2, const float* __restrict__ c2,
    float* __restrict__ A) {
  int wave = threadIdx.x >> 6;
  int lane = threadIdx.x & 63;
  int hp = lane >> 5, j = lane & 31;
  int node = blockIdx.x * 4 + wave;
  if (node >= N_NODES) return;
  float uwa = u2[j * 4 + hp];
  float uwb = u2[j * 4 + hp + 2];
  float cba = c2[hp];
  float cbb = c2[hp + 2];
  float hd = h1[(size_t)node * 32 + j];
  int e0 = rowstart[node];
  int e1 = e0 + deg[node];
  float acca = 0.f, accb = 0.f;
  for (int p = e0; p < e1; p++) {
    int s = src_perm[p];
    float f = h1[(size_t)s * 32 + j];
    float t = f - hd;
    float va = t * uwa;
    float vb = t * uwb;
#pragma unroll
    for (int msk = 1; msk <= 16; msk <<= 1) {
      va += __shfl_xor(va, msk, 64);
      vb += __shfl_xor(vb, msk, 64);
    }
    float la = va + cba;  // head hp
    float lb = vb + cbb;  // head hp+2
    float m = fmaxf(la, lb);
    m = fmaxf(m, __shfl_xor(m, 32, 64));  // max over all 4 heads
    float ea = __expf(la - m);
    float eb = __expf(lb - m);
    float es = ea + eb;
    es += __shfl_xor(es, 32, 64);         // sum over all 4 heads
    float inv = 1.f / es;
    acca += (ea * inv) * f;
    accb += (eb * inv) * f;
  }
  A[(size_t)node * 128 + hp * 32 + j] = acca;        // head hp
  A[(size_t)node * 128 + (hp + 2) * 32 + j] = accb;  // head hp+2
}

// ============ GEMM1: h1 = relu((A1 @ B1)/deg + b1), A1:[N,64], B1:[64,32] ============
// thread = (2 nodes, 4 channels); weights float4 from LDS shared by both nodes.
__global__ __launch_bounds__(256) void gemm1_kernel(
    const int* __restrict__ deg, const float* __restrict__ A,
    const float* __restrict__ w1, const float* __restrict__ b1,
    float* __restrict__ h1) {
  __shared__ float sB[64 * 32];  // 8 KB; sB[k][c] = B1[k][c]
  for (int i = threadIdx.x; i < 64 * 32; i += 256) {
    int hj = i / 32, c = i % 32;
    sB[i] = w1[(hj % 16) * 128 + (hj / 16) * 32 + c];
  }
  __syncthreads();
  const float4* sB4 = reinterpret_cast<const float4*>(sB);
  int c4 = threadIdx.x & 7;       // 8 float4 slots = 32 channels
  int g = threadIdx.x >> 3;       // 32 groups x 2 nodes = 64 nodes/block
  int n0 = blockIdx.x * 64 + g * 2;
  int n1 = n0 + 1;
  float4 bc = reinterpret_cast<const float4*>(b1)[c4];
  float4 acc0 = {0, 0, 0, 0}, acc1 = {0, 0, 0, 0};
  const float4* A0 = reinterpret_cast<const float4*>(A + (size_t)n0 * 64);
  const float4* A1 = reinterpret_cast<const float4*>(A + (size_t)n1 * 64);
  bool v0 = n0 < N_NODES, v1 = n1 < N_NODES;
#pragma unroll
  for (int k4 = 0; k4 < 16; k4++) {
    float4 a0 = v0 ? A0[k4] : make_float4(0, 0, 0, 0);
    float4 a1 = v1 ? A1[k4] : make_float4(0, 0, 0, 0);
    float4 w0 = sB4[(4 * k4 + 0) * 8 + c4];
    float4 wv1 = sB4[(4 * k4 + 1) * 8 + c4];
    float4 w2v = sB4[(4 * k4 + 2) * 8 + c4];
    float4 w3 = sB4[(4 * k4 + 3) * 8 + c4];
    acc0.x += a0.x * w0.x + a0.y * wv1.x + a0.z * w2v.x + a0.w * w3.x;
    acc0.y += a0.x * w0.y + a0.y * wv1.y + a0.z * w2v.y + a0.w * w3.y;
    acc0.z += a0.x * w0.z + a0.y * wv1.z + a0.z * w2v.z + a0.w * w3.z;
    acc0.w += a0.x * w0.w + a0.y * wv1.w + a0.z * w2v.w + a0.w * w3.w;
    acc1.x += a1.x * w0.x + a1.y * wv1.x + a1.z * w2v.x + a1.w * w3.x;
    acc1.y += a1.x * w0.y + a1.y * wv1.y + a1.z * w2v.y + a1.w * w3.y;
    acc1.z += a1.x * w0.z + a1.y * wv1.z + a1.z * w2v.z + a1.w * w3.z;
    acc1.w += a1.x * w0.w + a1.y * wv1.w + a1.z * w2v.w + a1.w * w3.w;
  }
  if (v0) {
    float inv = 1.f / fmaxf((float)deg[n0], 1.f);
    float4 o = {fmaxf(acc0.x * inv + bc.x, 0.f), fmaxf(acc0.y * inv + bc.y, 0.f),
                fmaxf(acc0.z * inv + bc.z, 0.f), fmaxf(acc0.w * inv + bc.w, 0.f)};
    reinterpret_cast<float4*>(h1 + (size_t)n0 * 32)[c4] = o;
  }
  if (v1) {
    float inv = 1.f / fmaxf((float)deg[n1], 1.f);
    float4 o = {fmaxf(acc1.x * inv + bc.x, 0.f), fmaxf(acc1.y * inv + bc.y, 0.f),
                fmaxf(acc1.z * inv + bc.z, 0.f), fmaxf(acc1.w * inv + bc.w, 0.f)};
    reinterpret_cast<float4*>(h1 + (size_t)n1 * 32)[c4] = o;
  }
}

// ============ GEMM2: h2 = relu((A2 @ B2)/deg + b2), A2:[N,128], B2:[128,64] ============
__global__ __launch_bounds__(256) void gemm2_kernel(
    const int* __restrict__ deg, const float* __restrict__ A,
    const float* __restrict__ w2, const float* __restrict__ b2,
    float* __restrict__ h2) {
  __shared__ float sB[128 * 64];  // 32 KB; sB[k][c] = B2[k][c]
  for (int i = threadIdx.x; i < 128 * 64; i += 256) {
    int hj = i / 64, c = i % 64;
    sB[i] = w2[(hj % 32) * 256 + (hj / 32) * 64 + c];
  }
  __syncthreads();
  const float4* sB4 = reinterpret_cast<const float4*>(sB);
  int c4 = threadIdx.x & 15;      // 16 float4 slots = 64 channels
  int g = threadIdx.x >> 4;       // 16 groups x 2 nodes = 32 nodes/tile
  float4 bc = reinterpret_cast<const float4*>(b2)[c4];
#pragma unroll
  for (int t = 0; t < 2; t++) {   // 64 nodes/block
    int n0 = blockIdx.x * 64 + t * 32 + g * 2;
    int n1 = n0 + 1;
    float4 acc0 = {0, 0, 0, 0}, acc1 = {0, 0, 0, 0};
    const float4* A0 = reinterpret_cast<const float4*>(A + (size_t)n0 * 128);
    const float4* A1 = reinterpret_cast<const float4*>(A + (size_t)n1 * 128);
    bool v0 = n0 < N_NODES, v1 = n1 < N_NODES;
#pragma unroll
    for (int k4 = 0; k4 < 32; k4++) {
      float4 a0 = v0 ? A0[k4] : make_float4(0, 0, 0, 0);
      float4 a1 = v1 ? A1[k4] : make_float4(0, 0, 0, 0);
      float4 w0 = sB4[(4 * k4 + 0) * 16 + c4];
      float4 wv1 = sB4[(4 * k4 + 1) * 16 + c4];
      float4 w2v = sB4[(4 * k4 + 2) * 16 + c4];
      float4 w3 = sB4[(4 * k4 + 3) * 16 + c4];
      acc0.x += a0.x * w0.x + a0.y * wv1.x + a0.z * w2v.x + a0.w * w3.x;
      acc0.y += a0.x * w0.y + a0.y * wv1.y + a0.z * w2v.y + a0.w * w3.y;
      acc0.z += a0.x * w0.z + a0.y * wv1.z + a0.z * w2v.z + a0.w * w3.z;
      acc0.w += a0.x * w0.w + a0.y * wv1.w + a0.z * w2v.w + a0.w * w3.w;
      acc1.x += a1.x * w0.x + a1.y * wv1.x + a1.z * w2v.x + a1.w * w3.x;
      acc1.y += a1.x * w0.y + a1.y * wv1.y + a1.z * w2v.y + a1.w * w3.y;
      acc1.z += a1.x * w0.z + a1.y * wv1.z + a1.z * w2v.z + a1.w * w3.z;
      acc1.w += a1.x * w0.w + a1.y * wv1.w + a1.z * w2v.w + a1.w * w3.w;
    }
    if (v0) {
      float inv = 1.f / fmaxf((float)deg[n0], 1.f);
      float4 o = {fmaxf(acc0.x * inv + bc.x, 0.f), fmaxf(acc0.y * inv + bc.y, 0.f),
                  fmaxf(acc0.z * inv + bc.z, 0.f), fmaxf(acc0.w * inv + bc.w, 0.f)};
      reinterpret_cast<float4*>(h2 + (size_t)n0 * 64)[c4] = o;
    }
    if (v1) {
      float inv = 1.f / fmaxf((float)deg[n1], 1.f);
      float4 o = {fmaxf(acc1.x * inv + bc.x, 0.f), fmaxf(acc1.y * inv + bc.y, 0.f),
                  fmaxf(acc1.z * inv + bc.z, 0.f), fmaxf(acc1.w * inv + bc.w, 0.f)};
      reinterpret_cast<float4*>(h2 + (size_t)n1 * 64)[c4] = o;
    }
  }
}

// ============ Pool: per-graph mean of h2 (batch sorted) ============
#define POOL_CHUNK 64
__global__ __launch_bounds__(256) void pool_kernel(
    const float* __restrict__ h2, const int* __restrict__ batch,
    float* __restrict__ gsum, float* __restrict__ gcnt) {
  int grp = threadIdx.x / 64;
  int c = threadIdx.x % 64;
  int n0 = (blockIdx.x * 4 + grp) * POOL_CHUNK;
  int n1 = min(n0 + POOL_CHUNK, N_NODES);
  if (n0 >= N_NODES) return;
  float acc = 0.f;
  float cacc = 0.f;
  int curg = batch[n0];
  for (int n = n0; n < n1; n++) {
    int g = batch[n];
    float v = h2[(size_t)n * 64 + c];
    if (g != curg) {
      atomicAdd(&gsum[curg * 64 + c], acc);
      if (c == 0) atomicAdd(&gcnt[curg], cacc);
      acc = 0.f;
      cacc = 0.f;
      curg = g;
    }
    acc += v;
    cacc += 1.f;
  }
  atomicAdd(&gsum[curg * 64 + c], acc);
  if (c == 0) atomicAdd(&gcnt[curg], cacc);
}

// ============ Head: out = (gsum/gcnt) @ fc1_w + fc1_b ============
__global__ __launch_bounds__(128) void head_kernel(
    const float* __restrict__ gsum, const float* __restrict__ gcnt,
    const float* __restrict__ fc1_w, const float* __restrict__ fc1_b,
    float* __restrict__ out) {
  int t = threadIdx.x;
  if (t >= NUM_GRAPHS * 10) return;
  int g = t / 10, k = t % 10;
  float inv = 1.f / fmaxf(gcnt[g], 1.f);
  float s = fc1_b[k];
#pragma unroll
  for (int c = 0; c < 64; c++) s += gsum[g * 64 + c] * inv * fc1_w[c * 10 + k];
  out[g * 10 + k] = s;
}

extern "C" void kernel_launch(void* const* d_in, const int* in_sizes, int n_in,
                              void* d_out, int out_size, void* d_ws, size_t ws_size,
                              hipStream_t stream) {
  const float* x = (const float*)d_in[0];
  const int* edge_index = (const int*)d_in[1];
  const int* batch = (const int*)d_in[2];
  const float* fc0_w = (const float*)d_in[3];
  const float* fc0_b = (const float*)d_in[4];
  const float* u1 = (const float*)d_in[5];
  const float* c1 = (const float*)d_in[6];
  const float* w1 = (const float*)d_in[7];
  const float* b1 = (const float*)d_in[8];
  const float* u2 = (const float*)d_in[9];
  const float* c2 = (const float*)d_in[10];
  const float* w2 = (const float*)d_in[11];
  const float* b2 = (const float*)d_in[12];
  const float* fc1_w = (const float*)d_in[13];
  const float* fc1_b = (const float*)d_in[14];
  float* out = (float*)d_out;

  const int* src = edge_index;            // x_j
  const int* dst = edge_index + N_EDGES;  // x_i

  // ---- workspace layout (4-byte words) ----
  char* wsb = (char*)d_ws;
  int* deg = (int*)wsb;                          // N    [memset with gctr]
  int* gctr = deg + N_NODES;                     // 1
  int* rowstart = (int*)wsb + 50004;             // N
  int* cursor = rowstart + N_NODES;              // N
  int* src_perm = cursor + N_NODES;              // E
  // words: 50004 + 2N + E = 950004
  float* h0 = (float*)wsb + 950004;              // N*16
  float* h1 = h0 + (size_t)N_NODES * 16;         // N*32
  float* h2 = h1 + (size_t)N_NODES * 32;         // N*64
  float* A = h2 + (size_t)N_NODES * 64;          // N*128 (layers 1 & 2)
  float* gsum = A + (size_t)N_NODES * 128;       // 8*64
  float* gcnt = gsum + NUM_GRAPHS * 64;          // 8

  hipMemsetAsync(deg, 0, (N_NODES + 1) * sizeof(int), stream);  // deg + gctr
  hipMemsetAsync(gsum, 0, (NUM_GRAPHS * 64 + NUM_GRAPHS) * sizeof(float), stream);

  int nblk = (N_NODES + 255) / 256;
  int eblk = (N_EDGES + 255) / 256;

  // CSR build
  hist_kernel<<<eblk, 256, 0, stream>>>(dst, deg);
  alloc_kernel<<<nblk, 256, 0, stream>>>(deg, gctr, rowstart, cursor);
  scatter_kernel<<<eblk, 256, 0, stream>>>(src, dst, cursor, src_perm);

  // Layer 0
  fc0_kernel<<<nblk, 256, 0, stream>>>(x, fc0_w, fc0_b, h0);

  // FeaStConv 1 (fused q+agg, then GEMM)
  agg1_fused<<<(N_NODES + 3) / 4, 256, 0, stream>>>(rowstart, deg, src_perm, h0, u1, c1, A);
  gemm1_kernel<<<(N_NODES + 63) / 64, 256, 0, stream>>>(deg, A, w1, b1, h1);

  // FeaStConv 2
  agg2_fused<<<(N_NODES + 3) / 4, 256, 0, stream>>>(rowstart, deg, src_perm, h1, u2, c2, A);
  gemm2_kernel<<<(N_NODES + 63) / 64, 256, 0, stream>>>(deg, A, w2, b2, h2);

  // Pool + head
  int pblk = (N_NODES + POOL_CHUNK * 4 - 1) / (POOL_CHUNK * 4);
  pool_kernel<<<pblk, 256, 0, stream>>>(h2, batch, gsum, gcnt);
  head_kernel<<<1, 128, 0, stream>>>(gsum, gcnt, fc1_w, fc1_b, out);
}

// Round 7
// 473.597 us; speedup vs baseline: 1.7106x; 1.7106x over previous
//
#include <hip/hip_runtime.h>

#define N_NODES 50000
#define N_EDGES 800000
#define HEADS 4
#define NUM_GRAPHS 8

// ============ CSR build ============
__global__ __launch_bounds__(256) void hist_kernel(const int* __restrict__ dst,
                                                   int* __restrict__ deg) {
  int e = blockIdx.x * blockDim.x + threadIdx.x;
  if (e < N_EDGES) atomicAdd(&deg[dst[e]], 1);
}

// Wave-aggregated bump allocation: rowstart[i] = arbitrary contiguous segment
// of length deg[i]. Cross-node order is irrelevant for correctness.
__global__ __launch_bounds__(256) void alloc_kernel(const int* __restrict__ deg,
                                                    int* __restrict__ gctr,
                                                    int* __restrict__ rowstart,
                                                    int* __restrict__ cursor) {
  int i = blockIdx.x * blockDim.x + threadIdx.x;
  int lane = threadIdx.x & 63;
  int d = (i < N_NODES) ? deg[i] : 0;
  int pre = d;
#pragma unroll
  for (int off = 1; off < 64; off <<= 1) {
    int v = __shfl_up(pre, off, 64);
    if (lane >= off) pre += v;
  }
  int total = __shfl(pre, 63, 64);
  int base = 0;
  if (lane == 63) base = atomicAdd(gctr, total);
  base = __shfl(base, 63, 64);
  if (i < N_NODES) {
    int start = base + pre - d;
    rowstart[i] = start;
    cursor[i] = start;
  }
}

// src_perm[slot] = src[e]  (the one unavoidable random scatter)
__global__ __launch_bounds__(256) void scatter_kernel(const int* __restrict__ src,
                                                      const int* __restrict__ dst,
                                                      int* __restrict__ cursor,
                                                      int* __restrict__ src_perm) {
  int e = blockIdx.x * blockDim.x + threadIdx.x;
  if (e >= N_EDGES) return;
  int p = atomicAdd(&cursor[dst[e]], 1);
  src_perm[p] = src[e];
}

// ============ fc0: h0 = relu(x@W0+b0) [N,16] ============
__global__ __launch_bounds__(256) void fc0_kernel(
    const float* __restrict__ x,
    const float* __restrict__ fc0_w, const float* __restrict__ fc0_b,
    float* __restrict__ h0) {
  __shared__ float sW0[3 * 16];
  __shared__ float sB0[16];
  for (int i = threadIdx.x; i < 48; i += blockDim.x) sW0[i] = fc0_w[i];
  for (int i = threadIdx.x; i < 16; i += blockDim.x) sB0[i] = fc0_b[i];
  __syncthreads();
  int n = blockIdx.x * blockDim.x + threadIdx.x;
  if (n >= N_NODES) return;
  float x0 = x[n * 3 + 0], x1 = x[n * 3 + 1], x2 = x[n * 3 + 2];
#pragma unroll
  for (int j = 0; j < 16; j++) {
    float v = x0 * sW0[0 * 16 + j] + x1 * sW0[1 * 16 + j] + x2 * sW0[2 * 16 + j] + sB0[j];
    h0[(size_t)n * 16 + j] = fmaxf(v, 0.f);
  }
}

// ============ Fused q+agg, layer 1 (CIN=16) ============
__global__ __launch_bounds__(256) void agg1_fused(
    const int* __restrict__ rowstart, const int* __restrict__ deg,
    const int* __restrict__ src_perm,
    const float* __restrict__ h0,
    const float* __restrict__ u1, const float* __restrict__ c1,
    float* __restrict__ A) {
  int wave = threadIdx.x >> 6;
  int lane = threadIdx.x & 63;
  int hh = lane >> 4, j = lane & 15;
  int node = blockIdx.x * 4 + wave;
  if (node >= N_NODES) return;
  float uw = u1[j * 4 + hh];
  float cbv = c1[hh];
  float hd = h0[(size_t)node * 16 + j];
  int e0 = rowstart[node];
  int e1 = e0 + deg[node];
  float acc = 0.f;
  for (int p = e0; p < e1; p++) {
    int s = src_perm[p];
    float f = h0[(size_t)s * 16 + j];
    float v = (f - hd) * uw;
    v += __shfl_xor(v, 1, 64);
    v += __shfl_xor(v, 2, 64);
    v += __shfl_xor(v, 4, 64);
    v += __shfl_xor(v, 8, 64);
    float logit = v + cbv;
    float m = logit;
    m = fmaxf(m, __shfl_xor(m, 16, 64));
    m = fmaxf(m, __shfl_xor(m, 32, 64));
    float ex = __expf(logit - m);
    float es = ex;
    es += __shfl_xor(es, 16, 64);
    es += __shfl_xor(es, 32, 64);
    acc += (ex / es) * f;
  }
  A[(size_t)node * 64 + lane] = acc;  // A[node][hh*16+j]
}

// ============ Fused q+agg, layer 2 (CIN=32) ============
__global__ __launch_bounds__(256) void agg2_fused(
    const int* __restrict__ rowstart, const int* __restrict__ deg,
    const int* __restrict__ src_perm,
    const float* __restrict__ h1,
    const float* __restrict__ u2, const float* __restrict__ c2,
    float* __restrict__ A) {
  int wave = threadIdx.x >> 6;
  int lane = threadIdx.x & 63;
  int hp = lane >> 5, j = lane & 31;
  int node = blockIdx.x * 4 + wave;
  if (node >= N_NODES) return;
  float uwa = u2[j * 4 + hp];
  float uwb = u2[j * 4 + hp + 2];
  float cba = c2[hp];
  float cbb = c2[hp + 2];
  float hd = h1[(size_t)node * 32 + j];
  int e0 = rowstart[node];
  int e1 = e0 + deg[node];
  float acca = 0.f, accb = 0.f;
  for (int p = e0; p < e1; p++) {
    int s = src_perm[p];
    float f = h1[(size_t)s * 32 + j];
    float t = f - hd;
    float va = t * uwa;
    float vb = t * uwb;
#pragma unroll
    for (int msk = 1; msk <= 16; msk <<= 1) {
      va += __shfl_xor(va, msk, 64);
      vb += __shfl_xor(vb, msk, 64);
    }
    float la = va + cba;  // head hp
    float lb = vb + cbb;  // head hp+2
    float m = fmaxf(la, lb);
    m = fmaxf(m, __shfl_xor(m, 32, 64));  // max over all 4 heads
    float ea = __expf(la - m);
    float eb = __expf(lb - m);
    float es = ea + eb;
    es += __shfl_xor(es, 32, 64);         // sum over all 4 heads
    float inv = 1.f / es;
    acca += (ea * inv) * f;
    accb += (eb * inv) * f;
  }
  A[(size_t)node * 128 + hp * 32 + j] = acca;        // head hp
  A[(size_t)node * 128 + (hp + 2) * 32 + j] = accb;  // head hp+2
}

// ============ GEMM1: h1 = relu((A1 @ B1)/deg + b1), A1:[N,64], B1:[64,32] ============
// thread = (2 nodes, 4 channels). Loads use clamped node index (always valid),
// stores are guarded. #pragma unroll 2 bounds in-flight registers.
__global__ __launch_bounds__(256) void gemm1_kernel(
    const int* __restrict__ deg, const float* __restrict__ A,
    const float* __restrict__ w1, const float* __restrict__ b1,
    float* __restrict__ h1) {
  __shared__ float sB[64 * 32];  // 8 KB; sB[k][c] = B1[k][c]
  for (int i = threadIdx.x; i < 64 * 32; i += 256) {
    int hj = i / 32, c = i % 32;
    sB[i] = w1[(hj % 16) * 128 + (hj / 16) * 32 + c];
  }
  __syncthreads();
  const float4* sB4 = reinterpret_cast<const float4*>(sB);
  int c4 = threadIdx.x & 7;       // 8 float4 slots = 32 channels
  int g = threadIdx.x >> 3;       // 32 pairs x 2 nodes = 64 nodes/block
  int n0 = blockIdx.x * 64 + g * 2;
  int n1 = n0 + 1;
  int na = min(n0, N_NODES - 1);
  int nb = min(n1, N_NODES - 1);
  const float4* A0 = reinterpret_cast<const float4*>(A + (size_t)na * 64);
  const float4* A1 = reinterpret_cast<const float4*>(A + (size_t)nb * 64);
  float4 bc = reinterpret_cast<const float4*>(b1)[c4];
  float4 acc0 = {0, 0, 0, 0}, acc1 = {0, 0, 0, 0};
#pragma unroll 2
  for (int k4 = 0; k4 < 16; k4++) {
    float4 a0 = A0[k4];
    float4 a1 = A1[k4];
    float4 w0 = sB4[(4 * k4 + 0) * 8 + c4];
    float4 wv1 = sB4[(4 * k4 + 1) * 8 + c4];
    float4 w2v = sB4[(4 * k4 + 2) * 8 + c4];
    float4 w3 = sB4[(4 * k4 + 3) * 8 + c4];
    acc0.x += a0.x * w0.x + a0.y * wv1.x + a0.z * w2v.x + a0.w * w3.x;
    acc0.y += a0.x * w0.y + a0.y * wv1.y + a0.z * w2v.y + a0.w * w3.y;
    acc0.z += a0.x * w0.z + a0.y * wv1.z + a0.z * w2v.z + a0.w * w3.z;
    acc0.w += a0.x * w0.w + a0.y * wv1.w + a0.z * w2v.w + a0.w * w3.w;
    acc1.x += a1.x * w0.x + a1.y * wv1.x + a1.z * w2v.x + a1.w * w3.x;
    acc1.y += a1.x * w0.y + a1.y * wv1.y + a1.z * w2v.y + a1.w * w3.y;
    acc1.z += a1.x * w0.z + a1.y * wv1.z + a1.z * w2v.z + a1.w * w3.z;
    acc1.w += a1.x * w0.w + a1.y * wv1.w + a1.z * w2v.w + a1.w * w3.w;
  }
  if (n0 < N_NODES) {
    float inv = 1.f / fmaxf((float)deg[n0], 1.f);
    float4 o = {fmaxf(acc0.x * inv + bc.x, 0.f), fmaxf(acc0.y * inv + bc.y, 0.f),
                fmaxf(acc0.z * inv + bc.z, 0.f), fmaxf(acc0.w * inv + bc.w, 0.f)};
    reinterpret_cast<float4*>(h1 + (size_t)n0 * 32)[c4] = o;
  }
  if (n1 < N_NODES) {
    float inv = 1.f / fmaxf((float)deg[n1], 1.f);
    float4 o = {fmaxf(acc1.x * inv + bc.x, 0.f), fmaxf(acc1.y * inv + bc.y, 0.f),
                fmaxf(acc1.z * inv + bc.z, 0.f), fmaxf(acc1.w * inv + bc.w, 0.f)};
    reinterpret_cast<float4*>(h1 + (size_t)n1 * 32)[c4] = o;
  }
}

// ============ GEMM2: h2 = relu((A2 @ B2)/deg + b2), A2:[N,128], B2:[128,64] ============
// thread = (2 nodes, 4 channels); 32 nodes/block; clamped loads, guarded stores.
__global__ __launch_bounds__(256) void gemm2_kernel(
    const int* __restrict__ deg, const float* __restrict__ A,
    const float* __restrict__ w2, const float* __restrict__ b2,
    float* __restrict__ h2) {
  __shared__ float sB[128 * 64];  // 32 KB; sB[k][c] = B2[k][c]
  for (int i = threadIdx.x; i < 128 * 64; i += 256) {
    int hj = i / 64, c = i % 64;
    sB[i] = w2[(hj % 32) * 256 + (hj / 32) * 64 + c];
  }
  __syncthreads();
  const float4* sB4 = reinterpret_cast<const float4*>(sB);
  int c4 = threadIdx.x & 15;      // 16 float4 slots = 64 channels
  int g = threadIdx.x >> 4;       // 16 pairs x 2 nodes = 32 nodes/block
  int n0 = blockIdx.x * 32 + g * 2;
  int n1 = n0 + 1;
  int na = min(n0, N_NODES - 1);
  int nb = min(n1, N_NODES - 1);
  const float4* A0 = reinterpret_cast<const float4*>(A + (size_t)na * 128);
  const float4* A1 = reinterpret_cast<const float4*>(A + (size_t)nb * 128);
  float4 bc = reinterpret_cast<const float4*>(b2)[c4];
  float4 acc0 = {0, 0, 0, 0}, acc1 = {0, 0, 0, 0};
#pragma unroll 2
  for (int k4 = 0; k4 < 32; k4++) {
    float4 a0 = A0[k4];
    float4 a1 = A1[k4];
    float4 w0 = sB4[(4 * k4 + 0) * 16 + c4];
    float4 wv1 = sB4[(4 * k4 + 1) * 16 + c4];
    float4 w2v = sB4[(4 * k4 + 2) * 16 + c4];
    float4 w3 = sB4[(4 * k4 + 3) * 16 + c4];
    acc0.x += a0.x * w0.x + a0.y * wv1.x + a0.z * w2v.x + a0.w * w3.x;
    acc0.y += a0.x * w0.y + a0.y * wv1.y + a0.z * w2v.y + a0.w * w3.y;
    acc0.z += a0.x * w0.z + a0.y * wv1.z + a0.z * w2v.z + a0.w * w3.z;
    acc0.w += a0.x * w0.w + a0.y * wv1.w + a0.z * w2v.w + a0.w * w3.w;
    acc1.x += a1.x * w0.x + a1.y * wv1.x + a1.z * w2v.x + a1.w * w3.x;
    acc1.y += a1.x * w0.y + a1.y * wv1.y + a1.z * w2v.y + a1.w * w3.y;
    acc1.z += a1.x * w0.z + a1.y * wv1.z + a1.z * w2v.z + a1.w * w3.z;
    acc1.w += a1.x * w0.w + a1.y * wv1.w + a1.z * w2v.w + a1.w * w3.w;
  }
  if (n0 < N_NODES) {
    float inv = 1.f / fmaxf((float)deg[n0], 1.f);
    float4 o = {fmaxf(acc0.x * inv + bc.x, 0.f), fmaxf(acc0.y * inv + bc.y, 0.f),
                fmaxf(acc0.z * inv + bc.z, 0.f), fmaxf(acc0.w * inv + bc.w, 0.f)};
    reinterpret_cast<float4*>(h2 + (size_t)n0 * 64)[c4] = o;
  }
  if (n1 < N_NODES) {
    float inv = 1.f / fmaxf((float)deg[n1], 1.f);
    float4 o = {fmaxf(acc1.x * inv + bc.x, 0.f), fmaxf(acc1.y * inv + bc.y, 0.f),
                fmaxf(acc1.z * inv + bc.z, 0.f), fmaxf(acc1.w * inv + bc.w, 0.f)};
    reinterpret_cast<float4*>(h2 + (size_t)n1 * 64)[c4] = o;
  }
}

// ============ Pool: per-graph mean of h2 (batch sorted) ============
#define POOL_CHUNK 64
__global__ __launch_bounds__(256) void pool_kernel(
    const float* __restrict__ h2, const int* __restrict__ batch,
    float* __restrict__ gsum, float* __restrict__ gcnt) {
  int grp = threadIdx.x / 64;
  int c = threadIdx.x % 64;
  int n0 = (blockIdx.x * 4 + grp) * POOL_CHUNK;
  int n1 = min(n0 + POOL_CHUNK, N_NODES);
  if (n0 >= N_NODES) return;
  float acc = 0.f;
  float cacc = 0.f;
  int curg = batch[n0];
  for (int n = n0; n < n1; n++) {
    int g = batch[n];
    float v = h2[(size_t)n * 64 + c];
    if (g != curg) {
      atomicAdd(&gsum[curg * 64 + c], acc);
      if (c == 0) atomicAdd(&gcnt[curg], cacc);
      acc = 0.f;
      cacc = 0.f;
      curg = g;
    }
    acc += v;
    cacc += 1.f;
  }
  atomicAdd(&gsum[curg * 64 + c], acc);
  if (c == 0) atomicAdd(&gcnt[curg], cacc);
}

// ============ Head: out = (gsum/gcnt) @ fc1_w + fc1_b ============
__global__ __launch_bounds__(128) void head_kernel(
    const float* __restrict__ gsum, const float* __restrict__ gcnt,
    const float* __restrict__ fc1_w, const float* __restrict__ fc1_b,
    float* __restrict__ out) {
  int t = threadIdx.x;
  if (t >= NUM_GRAPHS * 10) return;
  int g = t / 10, k = t % 10;
  float inv = 1.f / fmaxf(gcnt[g], 1.f);
  float s = fc1_b[k];
#pragma unroll
  for (int c = 0; c < 64; c++) s += gsum[g * 64 + c] * inv * fc1_w[c * 10 + k];
  out[g * 10 + k] = s;
}

extern "C" void kernel_launch(void* const* d_in, const int* in_sizes, int n_in,
                              void* d_out, int out_size, void* d_ws, size_t ws_size,
                              hipStream_t stream) {
  const float* x = (const float*)d_in[0];
  const int* edge_index = (const int*)d_in[1];
  const int* batch = (const int*)d_in[2];
  const float* fc0_w = (const float*)d_in[3];
  const float* fc0_b = (const float*)d_in[4];
  const float* u1 = (const float*)d_in[5];
  const float* c1 = (const float*)d_in[6];
  const float* w1 = (const float*)d_in[7];
  const float* b1 = (const float*)d_in[8];
  const float* u2 = (const float*)d_in[9];
  const float* c2 = (const float*)d_in[10];
  const float* w2 = (const float*)d_in[11];
  const float* b2 = (const float*)d_in[12];
  const float* fc1_w = (const float*)d_in[13];
  const float* fc1_b = (const float*)d_in[14];
  float* out = (float*)d_out;

  const int* src = edge_index;            // x_j
  const int* dst = edge_index + N_EDGES;  // x_i

  // ---- workspace layout (4-byte words) ----
  char* wsb = (char*)d_ws;
  int* deg = (int*)wsb;                          // N    [memset with gctr]
  int* gctr = deg + N_NODES;                     // 1
  int* rowstart = (int*)wsb + 50004;             // N
  int* cursor = rowstart + N_NODES;              // N
  int* src_perm = cursor + N_NODES;              // E
  // words: 50004 + 2N + E = 950004
  float* h0 = (float*)wsb + 950004;              // N*16
  float* h1 = h0 + (size_t)N_NODES * 16;         // N*32
  float* h2 = h1 + (size_t)N_NODES * 32;         // N*64
  float* A = h2 + (size_t)N_NODES * 64;          // N*128 (layers 1 & 2)
  float* gsum = A + (size_t)N_NODES * 128;       // 8*64
  float* gcnt = gsum + NUM_GRAPHS * 64;          // 8

  hipMemsetAsync(deg, 0, (N_NODES + 1) * sizeof(int), stream);  // deg + gctr
  hipMemsetAsync(gsum, 0, (NUM_GRAPHS * 64 + NUM_GRAPHS) * sizeof(float), stream);

  int nblk = (N_NODES + 255) / 256;
  int eblk = (N_EDGES + 255) / 256;

  // CSR build
  hist_kernel<<<eblk, 256, 0, stream>>>(dst, deg);
  alloc_kernel<<<nblk, 256, 0, stream>>>(deg, gctr, rowstart, cursor);
  scatter_kernel<<<eblk, 256, 0, stream>>>(src, dst, cursor, src_perm);

  // Layer 0
  fc0_kernel<<<nblk, 256, 0, stream>>>(x, fc0_w, fc0_b, h0);

  // FeaStConv 1 (fused q+agg, then GEMM)
  agg1_fused<<<(N_NODES + 3) / 4, 256, 0, stream>>>(rowstart, deg, src_perm, h0, u1, c1, A);
  gemm1_kernel<<<(N_NODES + 63) / 64, 256, 0, stream>>>(deg, A, w1, b1, h1);

  // FeaStConv 2
  agg2_fused<<<(N_NODES + 3) / 4, 256, 0, stream>>>(rowstart, deg, src_perm, h1, u2, c2, A);
  gemm2_kernel<<<(N_NODES + 31) / 32, 256, 0, stream>>>(deg, A, w2, b2, h2);

  // Pool + head
  int pblk = (N_NODES + POOL_CHUNK * 4 - 1) / (POOL_CHUNK * 4);
  pool_kernel<<<pblk, 256, 0, stream>>>(h2, batch, gsum, gcnt);
  head_kernel<<<1, 128, 0, stream>>>(gsum, gcnt, fc1_w, fc1_b, out);
}

// Round 8
// 388.734 us; speedup vs baseline: 2.0841x; 1.2183x over previous
//
#include <hip/hip_runtime.h>

#define N_NODES 50000
#define N_EDGES 800000
#define HEADS 4
#define NUM_GRAPHS 8

// ============ CSR build ============
__global__ __launch_bounds__(256) void hist_kernel(const int* __restrict__ dst,
                                                   int* __restrict__ deg) {
  int e = blockIdx.x * blockDim.x + threadIdx.x;
  if (e < N_EDGES) atomicAdd(&deg[dst[e]], 1);
}

// Wave-aggregated bump allocation: rowstart[i] = arbitrary contiguous segment
// of length deg[i]. Cross-node order is irrelevant for correctness.
__global__ __launch_bounds__(256) void alloc_kernel(const int* __restrict__ deg,
                                                    int* __restrict__ gctr,
                                                    int* __restrict__ rowstart,
                                                    int* __restrict__ cursor) {
  int i = blockIdx.x * blockDim.x + threadIdx.x;
  int lane = threadIdx.x & 63;
  int d = (i < N_NODES) ? deg[i] : 0;
  int pre = d;
#pragma unroll
  for (int off = 1; off < 64; off <<= 1) {
    int v = __shfl_up(pre, off, 64);
    if (lane >= off) pre += v;
  }
  int total = __shfl(pre, 63, 64);
  int base = 0;
  if (lane == 63) base = atomicAdd(gctr, total);
  base = __shfl(base, 63, 64);
  if (i < N_NODES) {
    int start = base + pre - d;
    rowstart[i] = start;
    cursor[i] = start;
  }
}

// src_perm[slot] = src[e]  (the one unavoidable random scatter)
__global__ __launch_bounds__(256) void scatter_kernel(const int* __restrict__ src,
                                                      const int* __restrict__ dst,
                                                      int* __restrict__ cursor,
                                                      int* __restrict__ src_perm) {
  int e = blockIdx.x * blockDim.x + threadIdx.x;
  if (e >= N_EDGES) return;
  int p = atomicAdd(&cursor[dst[e]], 1);
  src_perm[p] = src[e];
}

// ============ fc0: h0 = relu(x@W0+b0) [N,16]; P1[n,h] = h0[n]·u1[:,h] ============
__global__ __launch_bounds__(256) void fc0_kernel(
    const float* __restrict__ x,
    const float* __restrict__ fc0_w, const float* __restrict__ fc0_b,
    const float* __restrict__ u1,
    float* __restrict__ h0, float* __restrict__ P1) {
  __shared__ float sW0[3 * 16];
  __shared__ float sB0[16];
  __shared__ float sU[16 * 4];
  for (int i = threadIdx.x; i < 48; i += blockDim.x) sW0[i] = fc0_w[i];
  for (int i = threadIdx.x; i < 16; i += blockDim.x) sB0[i] = fc0_b[i];
  for (int i = threadIdx.x; i < 64; i += blockDim.x) sU[i] = u1[i];
  __syncthreads();
  int n = blockIdx.x * blockDim.x + threadIdx.x;
  if (n >= N_NODES) return;
  float x0 = x[n * 3 + 0], x1 = x[n * 3 + 1], x2 = x[n * 3 + 2];
  float h[16];
#pragma unroll
  for (int j = 0; j < 16; j++) {
    float v = x0 * sW0[0 * 16 + j] + x1 * sW0[1 * 16 + j] + x2 * sW0[2 * 16 + j] + sB0[j];
    h[j] = fmaxf(v, 0.f);
    h0[(size_t)n * 16 + j] = h[j];
  }
  float p0 = 0.f, p1 = 0.f, p2 = 0.f, p3 = 0.f;
#pragma unroll
  for (int j = 0; j < 16; j++) {
    p0 += h[j] * sU[j * 4 + 0];
    p1 += h[j] * sU[j * 4 + 1];
    p2 += h[j] * sU[j * 4 + 2];
    p3 += h[j] * sU[j * 4 + 3];
  }
  reinterpret_cast<float4*>(P1)[n] = make_float4(p0, p1, p2, p3);
}

// ============ proj2: P2[n,h] = h1[n]·u2[:,h]  (CIN=32) ============
__global__ __launch_bounds__(256) void proj2_kernel(
    const float* __restrict__ h1, const float* __restrict__ u2,
    float* __restrict__ P2) {
  __shared__ float sU[32 * 4];
  for (int i = threadIdx.x; i < 128; i += blockDim.x) sU[i] = u2[i];
  __syncthreads();
  int n = blockIdx.x * blockDim.x + threadIdx.x;
  if (n >= N_NODES) return;
  const float4* hr = reinterpret_cast<const float4*>(h1 + (size_t)n * 32);
  float p0 = 0.f, p1 = 0.f, p2 = 0.f, p3 = 0.f;
#pragma unroll
  for (int j4 = 0; j4 < 8; j4++) {
    float4 a = hr[j4];
#pragma unroll
    for (int k = 0; k < 4; k++) {
      float hv = k == 0 ? a.x : k == 1 ? a.y : k == 2 ? a.z : a.w;
      int j = 4 * j4 + k;
      p0 += hv * sU[j * 4 + 0];
      p1 += hv * sU[j * 4 + 1];
      p2 += hv * sU[j * 4 + 2];
      p3 += hv * sU[j * 4 + 3];
    }
  }
  reinterpret_cast<float4*>(P2)[n] = make_float4(p0, p1, p2, p3);
}

// ============ Fused q+agg, layer 1 (CIN=16): shuffle-free softmax via P ============
// One wave per node, lane = hh*16 + j. q[e,:] computed per-lane from
// P1[s] - P1[d] + c (wave-uniform float4 broadcast load). No DS ops in loop.
__global__ __launch_bounds__(256) void agg1_fused(
    const int* __restrict__ rowstart, const int* __restrict__ deg,
    const int* __restrict__ src_perm,
    const float* __restrict__ h0, const float* __restrict__ P1,
    const float* __restrict__ c1,
    float* __restrict__ A) {
  int wave = threadIdx.x >> 6;
  int lane = threadIdx.x & 63;
  int hh = lane >> 4;
  int j = lane & 15;
  int node = blockIdx.x * 4 + wave;
  if (node >= N_NODES) return;
  float4 Pd = reinterpret_cast<const float4*>(P1)[node];
  float b0 = c1[0] - Pd.x, b1 = c1[1] - Pd.y, b2 = c1[2] - Pd.z, b3 = c1[3] - Pd.w;
  int e0 = rowstart[node];
  int e1 = e0 + deg[node];
  float acc = 0.f;
  int p = e0;
  for (; p + 2 <= e1; p += 2) {
    int s0 = src_perm[p];
    int s1 = src_perm[p + 1];
    float4 Pa = reinterpret_cast<const float4*>(P1)[s0];
    float4 Pb = reinterpret_cast<const float4*>(P1)[s1];
    float fa = h0[(size_t)s0 * 16 + j];
    float fb = h0[(size_t)s1 * 16 + j];
    // edge a
    float l0 = Pa.x + b0, l1 = Pa.y + b1, l2 = Pa.z + b2, l3 = Pa.w + b3;
    float m = fmaxf(fmaxf(l0, l1), fmaxf(l2, l3));
    float e0a = __expf(l0 - m), e1a = __expf(l1 - m), e2a = __expf(l2 - m), e3a = __expf(l3 - m);
    float inv = 1.f / (e0a + e1a + e2a + e3a);
    float q = (hh == 0 ? e0a : hh == 1 ? e1a : hh == 2 ? e2a : e3a) * inv;
    acc += q * fa;
    // edge b
    l0 = Pb.x + b0; l1 = Pb.y + b1; l2 = Pb.z + b2; l3 = Pb.w + b3;
    m = fmaxf(fmaxf(l0, l1), fmaxf(l2, l3));
    e0a = __expf(l0 - m); e1a = __expf(l1 - m); e2a = __expf(l2 - m); e3a = __expf(l3 - m);
    inv = 1.f / (e0a + e1a + e2a + e3a);
    q = (hh == 0 ? e0a : hh == 1 ? e1a : hh == 2 ? e2a : e3a) * inv;
    acc += q * fb;
  }
  for (; p < e1; p++) {
    int s = src_perm[p];
    float4 Ps = reinterpret_cast<const float4*>(P1)[s];
    float f = h0[(size_t)s * 16 + j];
    float l0 = Ps.x + b0, l1 = Ps.y + b1, l2 = Ps.z + b2, l3 = Ps.w + b3;
    float m = fmaxf(fmaxf(l0, l1), fmaxf(l2, l3));
    float e0a = __expf(l0 - m), e1a = __expf(l1 - m), e2a = __expf(l2 - m), e3a = __expf(l3 - m);
    float inv = 1.f / (e0a + e1a + e2a + e3a);
    float q = (hh == 0 ? e0a : hh == 1 ? e1a : hh == 2 ? e2a : e3a) * inv;
    acc += q * f;
  }
  A[(size_t)node * 64 + lane] = acc;  // A[node][hh*16+j]
}

// ============ Fused q+agg, layer 2 (CIN=32): shuffle-free softmax via P ============
// One wave per node, lane = hp*32 + j covers heads {hp, hp+2}.
__global__ __launch_bounds__(256) void agg2_fused(
    const int* __restrict__ rowstart, const int* __restrict__ deg,
    const int* __restrict__ src_perm,
    const float* __restrict__ h1, const float* __restrict__ P2,
    const float* __restrict__ c2,
    float* __restrict__ A) {
  int wave = threadIdx.x >> 6;
  int lane = threadIdx.x & 63;
  int hp = lane >> 5;
  int j = lane & 31;
  int node = blockIdx.x * 4 + wave;
  if (node >= N_NODES) return;
  float4 Pd = reinterpret_cast<const float4*>(P2)[node];
  float b0 = c2[0] - Pd.x, b1 = c2[1] - Pd.y, b2 = c2[2] - Pd.z, b3 = c2[3] - Pd.w;
  int e0 = rowstart[node];
  int e1 = e0 + deg[node];
  float acca = 0.f, accb = 0.f;
  int p = e0;
  for (; p + 2 <= e1; p += 2) {
    int s0 = src_perm[p];
    int s1 = src_perm[p + 1];
    float4 Pa = reinterpret_cast<const float4*>(P2)[s0];
    float4 Pb = reinterpret_cast<const float4*>(P2)[s1];
    float fa = h1[(size_t)s0 * 32 + j];
    float fb = h1[(size_t)s1 * 32 + j];
    // edge a
    float l0 = Pa.x + b0, l1 = Pa.y + b1, l2 = Pa.z + b2, l3 = Pa.w + b3;
    float m = fmaxf(fmaxf(l0, l1), fmaxf(l2, l3));
    float e0a = __expf(l0 - m), e1a = __expf(l1 - m), e2a = __expf(l2 - m), e3a = __expf(l3 - m);
    float inv = 1.f / (e0a + e1a + e2a + e3a);
    float qa = (hp == 0 ? e0a : e1a) * inv;   // head hp
    float qb = (hp == 0 ? e2a : e3a) * inv;   // head hp+2
    acca += qa * fa;
    accb += qb * fa;
    // edge b
    l0 = Pb.x + b0; l1 = Pb.y + b1; l2 = Pb.z + b2; l3 = Pb.w + b3;
    m = fmaxf(fmaxf(l0, l1), fmaxf(l2, l3));
    e0a = __expf(l0 - m); e1a = __expf(l1 - m); e2a = __expf(l2 - m); e3a = __expf(l3 - m);
    inv = 1.f / (e0a + e1a + e2a + e3a);
    qa = (hp == 0 ? e0a : e1a) * inv;
    qb = (hp == 0 ? e2a : e3a) * inv;
    acca += qa * fb;
    accb += qb * fb;
  }
  for (; p < e1; p++) {
    int s = src_perm[p];
    float4 Ps = reinterpret_cast<const float4*>(P2)[s];
    float f = h1[(size_t)s * 32 + j];
    float l0 = Ps.x + b0, l1 = Ps.y + b1, l2 = Ps.z + b2, l3 = Ps.w + b3;
    float m = fmaxf(fmaxf(l0, l1), fmaxf(l2, l3));
    float e0a = __expf(l0 - m), e1a = __expf(l1 - m), e2a = __expf(l2 - m), e3a = __expf(l3 - m);
    float inv = 1.f / (e0a + e1a + e2a + e3a);
    float qa = (hp == 0 ? e0a : e1a) * inv;
    float qb = (hp == 0 ? e2a : e3a) * inv;
    acca += qa * f;
    accb += qb * f;
  }
  A[(size_t)node * 128 + hp * 32 + j] = acca;        // head hp
  A[(size_t)node * 128 + (hp + 2) * 32 + j] = accb;  // head hp+2
}

// ============ GEMM1: h1 = relu((A1 @ B1)/deg + b1), A1:[N,64], B1:[64,32] ============
__global__ __launch_bounds__(256) void gemm1_kernel(
    const int* __restrict__ deg, const float* __restrict__ A,
    const float* __restrict__ w1, const float* __restrict__ b1,
    float* __restrict__ h1) {
  __shared__ float sB[64 * 32];  // 8 KB; sB[k][c] = B1[k][c]
  for (int i = threadIdx.x; i < 64 * 32; i += 256) {
    int hj = i / 32, c = i % 32;
    sB[i] = w1[(hj % 16) * 128 + (hj / 16) * 32 + c];
  }
  __syncthreads();
  const float4* sB4 = reinterpret_cast<const float4*>(sB);
  int c4 = threadIdx.x & 7;       // 8 float4 slots = 32 channels
  int g = threadIdx.x >> 3;       // 32 pairs x 2 nodes = 64 nodes/block
  int n0 = blockIdx.x * 64 + g * 2;
  int n1 = n0 + 1;
  int na = min(n0, N_NODES - 1);
  int nb = min(n1, N_NODES - 1);
  const float4* A0 = reinterpret_cast<const float4*>(A + (size_t)na * 64);
  const float4* A1 = reinterpret_cast<const float4*>(A + (size_t)nb * 64);
  float4 bc = reinterpret_cast<const float4*>(b1)[c4];
  float4 acc0 = {0, 0, 0, 0}, acc1 = {0, 0, 0, 0};
#pragma unroll 2
  for (int k4 = 0; k4 < 16; k4++) {
    float4 a0 = A0[k4];
    float4 a1 = A1[k4];
    float4 w0 = sB4[(4 * k4 + 0) * 8 + c4];
    float4 wv1 = sB4[(4 * k4 + 1) * 8 + c4];
    float4 w2v = sB4[(4 * k4 + 2) * 8 + c4];
    float4 w3 = sB4[(4 * k4 + 3) * 8 + c4];
    acc0.x += a0.x * w0.x + a0.y * wv1.x + a0.z * w2v.x + a0.w * w3.x;
    acc0.y += a0.x * w0.y + a0.y * wv1.y + a0.z * w2v.y + a0.w * w3.y;
    acc0.z += a0.x * w0.z + a0.y * wv1.z + a0.z * w2v.z + a0.w * w3.z;
    acc0.w += a0.x * w0.w + a0.y * wv1.w + a0.z * w2v.w + a0.w * w3.w;
    acc1.x += a1.x * w0.x + a1.y * wv1.x + a1.z * w2v.x + a1.w * w3.x;
    acc1.y += a1.x * w0.y + a1.y * wv1.y + a1.z * w2v.y + a1.w * w3.y;
    acc1.z += a1.x * w0.z + a1.y * wv1.z + a1.z * w2v.z + a1.w * w3.z;
    acc1.w += a1.x * w0.w + a1.y * wv1.w + a1.z * w2v.w + a1.w * w3.w;
  }
  if (n0 < N_NODES) {
    float inv = 1.f / fmaxf((float)deg[n0], 1.f);
    float4 o = {fmaxf(acc0.x * inv + bc.x, 0.f), fmaxf(acc0.y * inv + bc.y, 0.f),
                fmaxf(acc0.z * inv + bc.z, 0.f), fmaxf(acc0.w * inv + bc.w, 0.f)};
    reinterpret_cast<float4*>(h1 + (size_t)n0 * 32)[c4] = o;
  }
  if (n1 < N_NODES) {
    float inv = 1.f / fmaxf((float)deg[n1], 1.f);
    float4 o = {fmaxf(acc1.x * inv + bc.x, 0.f), fmaxf(acc1.y * inv + bc.y, 0.f),
                fmaxf(acc1.z * inv + bc.z, 0.f), fmaxf(acc1.w * inv + bc.w, 0.f)};
    reinterpret_cast<float4*>(h1 + (size_t)n1 * 32)[c4] = o;
  }
}

// ============ GEMM2: h2 = relu((A2 @ B2)/deg + b2), A2:[N,128], B2:[128,64] ============
__global__ __launch_bounds__(256) void gemm2_kernel(
    const int* __restrict__ deg, const float* __restrict__ A,
    const float* __restrict__ w2, const float* __restrict__ b2,
    float* __restrict__ h2) {
  __shared__ float sB[128 * 64];  // 32 KB; sB[k][c] = B2[k][c]
  for (int i = threadIdx.x; i < 128 * 64; i += 256) {
    int hj = i / 64, c = i % 64;
    sB[i] = w2[(hj % 32) * 256 + (hj / 32) * 64 + c];
  }
  __syncthreads();
  const float4* sB4 = reinterpret_cast<const float4*>(sB);
  int c4 = threadIdx.x & 15;      // 16 float4 slots = 64 channels
  int g = threadIdx.x >> 4;       // 16 pairs x 2 nodes = 32 nodes/block
  int n0 = blockIdx.x * 32 + g * 2;
  int n1 = n0 + 1;
  int na = min(n0, N_NODES - 1);
  int nb = min(n1, N_NODES - 1);
  const float4* A0 = reinterpret_cast<const float4*>(A + (size_t)na * 128);
  const float4* A1 = reinterpret_cast<const float4*>(A + (size_t)nb * 128);
  float4 bc = reinterpret_cast<const float4*>(b2)[c4];
  float4 acc0 = {0, 0, 0, 0}, acc1 = {0, 0, 0, 0};
#pragma unroll 2
  for (int k4 = 0; k4 < 32; k4++) {
    float4 a0 = A0[k4];
    float4 a1 = A1[k4];
    float4 w0 = sB4[(4 * k4 + 0) * 16 + c4];
    float4 wv1 = sB4[(4 * k4 + 1) * 16 + c4];
    float4 w2v = sB4[(4 * k4 + 2) * 16 + c4];
    float4 w3 = sB4[(4 * k4 + 3) * 16 + c4];
    acc0.x += a0.x * w0.x + a0.y * wv1.x + a0.z * w2v.x + a0.w * w3.x;
    acc0.y += a0.x * w0.y + a0.y * wv1.y + a0.z * w2v.y + a0.w * w3.y;
    acc0.z += a0.x * w0.z + a0.y * wv1.z + a0.z * w2v.z + a0.w * w3.z;
    acc0.w += a0.x * w0.w + a0.y * wv1.w + a0.z * w2v.w + a0.w * w3.w;
    acc1.x += a1.x * w0.x + a1.y * wv1.x + a1.z * w2v.x + a1.w * w3.x;
    acc1.y += a1.x * w0.y + a1.y * wv1.y + a1.z * w2v.y + a1.w * w3.y;
    acc1.z += a1.x * w0.z + a1.y * wv1.z + a1.z * w2v.z + a1.w * w3.z;
    acc1.w += a1.x * w0.w + a1.y * wv1.w + a1.z * w2v.w + a1.w * w3.w;
  }
  if (n0 < N_NODES) {
    float inv = 1.f / fmaxf((float)deg[n0], 1.f);
    float4 o = {fmaxf(acc0.x * inv + bc.x, 0.f), fmaxf(acc0.y * inv + bc.y, 0.f),
                fmaxf(acc0.z * inv + bc.z, 0.f), fmaxf(acc0.w * inv + bc.w, 0.f)};
    reinterpret_cast<float4*>(h2 + (size_t)n0 * 64)[c4] = o;
  }
  if (n1 < N_NODES) {
    float inv = 1.f / fmaxf((float)deg[n1], 1.f);
    float4 o = {fmaxf(acc1.x * inv + bc.x, 0.f), fmaxf(acc1.y * inv + bc.y, 0.f),
                fmaxf(acc1.z * inv + bc.z, 0.f), fmaxf(acc1.w * inv + bc.w, 0.f)};
    reinterpret_cast<float4*>(h2 + (size_t)n1 * 64)[c4] = o;
  }
}

// ============ Pool: per-graph mean of h2 (batch sorted) ============
#define POOL_CHUNK 64
__global__ __launch_bounds__(256) void pool_kernel(
    const float* __restrict__ h2, const int* __restrict__ batch,
    float* __restrict__ gsum, float* __restrict__ gcnt) {
  int grp = threadIdx.x / 64;
  int c = threadIdx.x % 64;
  int n0 = (blockIdx.x * 4 + grp) * POOL_CHUNK;
  int n1 = min(n0 + POOL_CHUNK, N_NODES);
  if (n0 >= N_NODES) return;
  float acc = 0.f;
  float cacc = 0.f;
  int curg = batch[n0];
  for (int n = n0; n < n1; n++) {
    int g = batch[n];
    float v = h2[(size_t)n * 64 + c];
    if (g != curg) {
      atomicAdd(&gsum[curg * 64 + c], acc);
      if (c == 0) atomicAdd(&gcnt[curg], cacc);
      acc = 0.f;
      cacc = 0.f;
      curg = g;
    }
    acc += v;
    cacc += 1.f;
  }
  atomicAdd(&gsum[curg * 64 + c], acc);
  if (c == 0) atomicAdd(&gcnt[curg], cacc);
}

// ============ Head: out = (gsum/gcnt) @ fc1_w + fc1_b ============
__global__ __launch_bounds__(128) void head_kernel(
    const float* __restrict__ gsum, const float* __restrict__ gcnt,
    const float* __restrict__ fc1_w, const float* __restrict__ fc1_b,
    float* __restrict__ out) {
  int t = threadIdx.x;
  if (t >= NUM_GRAPHS * 10) return;
  int g = t / 10, k = t % 10;
  float inv = 1.f / fmaxf(gcnt[g], 1.f);
  float s = fc1_b[k];
#pragma unroll
  for (int c = 0; c < 64; c++) s += gsum[g * 64 + c] * inv * fc1_w[c * 10 + k];
  out[g * 10 + k] = s;
}

extern "C" void kernel_launch(void* const* d_in, const int* in_sizes, int n_in,
                              void* d_out, int out_size, void* d_ws, size_t ws_size,
                              hipStream_t stream) {
  const float* x = (const float*)d_in[0];
  const int* edge_index = (const int*)d_in[1];
  const int* batch = (const int*)d_in[2];
  const float* fc0_w = (const float*)d_in[3];
  const float* fc0_b = (const float*)d_in[4];
  const float* u1 = (const float*)d_in[5];
  const float* c1 = (const float*)d_in[6];
  const float* w1 = (const float*)d_in[7];
  const float* b1 = (const float*)d_in[8];
  const float* u2 = (const float*)d_in[9];
  const float* c2 = (const float*)d_in[10];
  const float* w2 = (const float*)d_in[11];
  const float* b2 = (const float*)d_in[12];
  const float* fc1_w = (const float*)d_in[13];
  const float* fc1_b = (const float*)d_in[14];
  float* out = (float*)d_out;

  const int* src = edge_index;            // x_j
  const int* dst = edge_index + N_EDGES;  // x_i

  // ---- workspace layout (4-byte words) ----
  char* wsb = (char*)d_ws;
  int* deg = (int*)wsb;                          // N    [memset with gctr]
  int* gctr = deg + N_NODES;                     // 1
  int* rowstart = (int*)wsb + 50004;             // N
  int* cursor = rowstart + N_NODES;              // N
  int* src_perm = cursor + N_NODES;              // E
  // words: 50004 + 2N + E = 950004
  float* h0 = (float*)wsb + 950004;              // N*16
  float* h1 = h0 + (size_t)N_NODES * 16;         // N*32
  float* h2 = h1 + (size_t)N_NODES * 32;         // N*64
  float* A = h2 + (size_t)N_NODES * 64;          // N*128 (layers 1 & 2)
  float* P1 = A + (size_t)N_NODES * 128;         // N*4
  float* P2 = P1 + (size_t)N_NODES * 4;          // N*4
  float* gsum = P2 + (size_t)N_NODES * 4;        // 8*64
  float* gcnt = gsum + NUM_GRAPHS * 64;          // 8

  hipMemsetAsync(deg, 0, (N_NODES + 1) * sizeof(int), stream);  // deg + gctr
  hipMemsetAsync(gsum, 0, (NUM_GRAPHS * 64 + NUM_GRAPHS) * sizeof(float), stream);

  int nblk = (N_NODES + 255) / 256;
  int eblk = (N_EDGES + 255) / 256;

  // CSR build
  hist_kernel<<<eblk, 256, 0, stream>>>(dst, deg);
  alloc_kernel<<<nblk, 256, 0, stream>>>(deg, gctr, rowstart, cursor);
  scatter_kernel<<<eblk, 256, 0, stream>>>(src, dst, cursor, src_perm);

  // Layer 0 (+ P1 projection)
  fc0_kernel<<<nblk, 256, 0, stream>>>(x, fc0_w, fc0_b, u1, h0, P1);

  // FeaStConv 1 (shuffle-free fused q+agg, then GEMM)
  agg1_fused<<<(N_NODES + 3) / 4, 256, 0, stream>>>(rowstart, deg, src_perm, h0, P1, c1, A);
  gemm1_kernel<<<(N_NODES + 63) / 64, 256, 0, stream>>>(deg, A, w1, b1, h1);

  // FeaStConv 2
  proj2_kernel<<<nblk, 256, 0, stream>>>(h1, u2, P2);
  agg2_fused<<<(N_NODES + 3) / 4, 256, 0, stream>>>(rowstart, deg, src_perm, h1, P2, c2, A);
  gemm2_kernel<<<(N_NODES + 31) / 32, 256, 0, stream>>>(deg, A, w2, b2, h2);

  // Pool + head
  int pblk = (N_NODES + POOL_CHUNK * 4 - 1) / (POOL_CHUNK * 4);
  pool_kernel<<<pblk, 256, 0, stream>>>(h2, batch, gsum, gcnt);
  head_kernel<<<1, 128, 0, stream>>>(gsum, gcnt, fc1_w, fc1_b, out);
}